// Round 5
// baseline (863.485 us; speedup 1.0000x reference)
//
#include <hip/hip_runtime.h>

#define BSZ 32
#define DIMD 256
#define WW 2048
#define SLOTS 1024
#define NROWS (BSZ*WW)
#define LOG_SLOTS 6.931471805599453f
#define THR 4.0f

#define ZQ_N (BSZ*DIMD*WW)
#define IDX_OFF ZQ_N
#define KL_OFF (ZQ_N + NROWS)
#define CM_OFF (KL_OFF + 1)

// workspace byte offsets
#define WS_CH   0u
#define WS_CL   524288u
#define WS_PV   1048576u
#define WS_CBSQ 1572864u
#define WS_TOP  1576960u
#define WS_MR   2625536u
#define WS_NORM 11014144u
#define WS_U    11538432u
#define WS_NEED (11538432ull + 134217728ull)

typedef _Float16 half2_t __attribute__((ext_vector_type(2)));
typedef _Float16 half8_t __attribute__((ext_vector_type(8)));
typedef float v4f __attribute__((ext_vector_type(4)));

__device__ __forceinline__ void pmerge(float& m, float& s, float& t, float om, float os, float ot) {
  float M = fmaxf(m, om);
  float ea = __expf(m - M), eb = __expf(om - M);
  s = s * ea + os * eb;
  t = t * ea + ot * eb;
  m = M;
}

__device__ __forceinline__ void top3_merge(float& v1, float& i1, float& v2, float& i2, float& v3,
                                           float ov1, float oi1, float ov2, float oi2, float ov3) {
  bool sw = (ov1 > v1) || (ov1 == v1 && oi1 < i1);
  float a1v = sw ? ov1 : v1, a1i = sw ? oi1 : i1;
  float a2v = sw ? ov2 : v2, a2i = sw ? oi2 : i2;
  float a3v = sw ? ov3 : v3;
  float b1v = sw ? v1 : ov1, b1i = sw ? i1 : oi1;
  float b2v = sw ? v2 : ov2;
  bool a2w = (a2v > b1v) || (a2v == b1v && a2i < b1i);
  v1 = a1v; i1 = a1i;
  v2 = a2w ? a2v : b1v;
  i2 = a2w ? a2i : b1i;
  v3 = a2w ? fmaxf(a3v, b1v) : fmaxf(a2v, b2v);
}

__global__ void k0_zero(float* out) { out[KL_OFF] = 0.f; out[CM_OFF] = 0.f; }

// pack codebook: chs/cls = fp16 hi/lo B-fragment stream for QK^T (chunk-contiguous 16KB tiles);
// pvs = fp16 A-fragment stream for PV; cbsq in fp64->fp32
__global__ void k2_pack(const float* __restrict__ cb, _Float16* __restrict__ chs,
                        _Float16* __restrict__ cls, _Float16* __restrict__ pvs,
                        float* __restrict__ cbsq) {
  const int tid = blockIdx.x * 256 + threadIdx.x;
  if (tid < 32768) {
    const int lane = tid & 63;
    {
      const int ks = (tid >> 6) & 7, sblk = tid >> 9;
      const int col = sblk * 16 + (lane & 15);
      const int k0 = ks * 32 + (lane >> 4) * 8;
      half8_t vh, vl;
#pragma unroll
      for (int j = 0; j < 8; ++j) {
        const float v = cb[(size_t)col * DIMD + k0 + j];
        const _Float16 h = (_Float16)v;
        vh[j] = h;
        vl[j] = (_Float16)(v - (float)h);
      }
      *(half8_t*)&chs[(size_t)tid * 8] = vh;
      *(half8_t*)&cls[(size_t)tid * 8] = vl;
    }
    {
      const int idx = tid >> 6;
      const int cf = idx >> 4, dt = idx & 15;
      const int d = dt * 16 + (lane & 15);
      const int s0 = cf * 32 + (lane >> 4) * 8;
      half8_t vp;
#pragma unroll
      for (int j = 0; j < 8; ++j)
        vp[j] = (_Float16)cb[(size_t)(s0 + j) * DIMD + d];
      *(half8_t*)&pvs[(size_t)tid * 8] = vp;
    }
  }
  if (tid < SLOTS) {
    double a = 0.0;
    for (int i = 0; i < DIMD; ++i) { const double v = (double)cb[(size_t)tid * DIMD + i]; a += v * v; }
    cbsq[tid] = (float)a;
  }
}

// async stage one 16KB chunk (hi+lo) of codebook fragments into LDS (linear, global_load_lds)
__device__ __forceinline__ void stage_chunk(const _Float16* __restrict__ chs,
                                            const _Float16* __restrict__ cls,
                                            _Float16* bsh, _Float16* bsl,
                                            int cf, int wv, int lane) {
  const size_t gbase = (size_t)cf * 8192 + wv * 2048 + lane * 8;
#pragma unroll
  for (int i = 0; i < 4; ++i) {
    __builtin_amdgcn_global_load_lds(
        (const __attribute__((address_space(1))) void*)(chs + gbase + i * 512),
        (__attribute__((address_space(3))) void*)(bsh + wv * 2048 + i * 512), 16, 0, 0);
    __builtin_amdgcn_global_load_lds(
        (const __attribute__((address_space(1))) void*)(cls + gbase + i * 512),
        (__attribute__((address_space(3))) void*)(bsl + wv * 2048 + i * 512), 16, 0, 0);
  }
}

// k3: QK^T (fp16-split MFMA, B staged in LDS) + online probs stats + top3 + u write (fp16)
__global__ __launch_bounds__(256) __attribute__((amdgpu_waves_per_eu(4, 4)))
void k3_main(const float* __restrict__ z_e, const float* __restrict__ gum,
             const _Float16* __restrict__ chs, const _Float16* __restrict__ cls,
             const float* __restrict__ cbsq, _Float16* __restrict__ ubig,
             float* __restrict__ mrbuf, float2* __restrict__ normbuf,
             float* __restrict__ topw, float* __restrict__ out) {
  __shared__ _Float16 bsh[8192];
  __shared__ _Float16 bsl[8192];
  __shared__ _Float16 ubuf[4][16][44];   // 88B row stride: 16 rows hit 16 distinct bank-starts

  const int t = threadIdx.x, wv = t >> 6, lane = t & 63, l15 = lane & 15, lq = lane >> 4;
  const int r0 = blockIdx.x * 64;
  const int rw = r0 + wv * 16;
  const int rt = blockIdx.x * 4 + wv;
  const int b = r0 >> 11;
  const int w0 = rw & 2047;

  stage_chunk(chs, cls, bsh, bsl, 0, wv, lane);

  // z fragments to registers (fp16 hi/lo split)
  const float* zbase = z_e + (size_t)b * DIMD * WW + w0 + l15;
  half8_t ah[8], al[8];
  float zacc = 0.f;
#pragma unroll
  for (int ks = 0; ks < 8; ++ks) {
#pragma unroll
    for (int j = 0; j < 8; ++j) {
      const float v = zbase[(size_t)(ks * 32 + lq * 8 + j) * WW];
      zacc += v * v;
      const _Float16 h = (_Float16)v;
      ah[ks][j] = h;
      al[ks][j] = (_Float16)(v - (float)h);
    }
  }
  zacc += __shfl_xor(zacc, 16);
  zacc += __shfl_xor(zacc, 32);
  float zs[4];
#pragma unroll
  for (int g = 0; g < 4; ++g) zs[g] = __shfl(zacc, lq * 4 + g);

  float m1[4], s1[4], t1[4], v1[4], v2[4], v3[4], i1[4], i2[4], s2[4], mr[4];
#pragma unroll
  for (int g = 0; g < 4; ++g) {
    m1[g] = -1e30f; s1[g] = 0.f; t1[g] = 0.f;
    v1[g] = -1e30f; v2[g] = -1e30f; v3[g] = -1e30f; i1[g] = 0.f; i2[g] = 0.f;
    s2[g] = 0.f; mr[g] = -1e30f;
  }

  const float* gbase = gum + (size_t)rw * SLOTS;
  float gc[8], cbc[2];
#pragma unroll
  for (int c = 0; c < 2; ++c) {
    cbc[c] = cbsq[c * 16 + l15];
#pragma unroll
    for (int g = 0; g < 4; ++g)
      gc[c * 4 + g] = gbase[(size_t)(lq * 4 + g) * SLOTS + c * 16 + l15];
  }

  __syncthreads();   // stage(0) complete

#pragma unroll 1
  for (int cf = 0; cf < 32; ++cf) {
    // S1: gum/cbsq prefetch for next chunk, then MFMAs on staged B
    float gn[8], cbn[2];
    if (cf < 31) {
#pragma unroll
      for (int c = 0; c < 2; ++c) {
        cbn[c] = cbsq[(cf + 1) * 32 + c * 16 + l15];
#pragma unroll
        for (int g = 0; g < 4; ++g)
          gn[c * 4 + g] = gbase[(size_t)(lq * 4 + g) * SLOTS + (cf + 1) * 32 + c * 16 + l15];
      }
    }
    v4f qh[2], ql[2];
    qh[0] = v4f{0.f, 0.f, 0.f, 0.f}; qh[1] = v4f{0.f, 0.f, 0.f, 0.f};
    ql[0] = v4f{0.f, 0.f, 0.f, 0.f}; ql[1] = v4f{0.f, 0.f, 0.f, 0.f};
#pragma unroll
    for (int ks = 0; ks < 8; ++ks) {
      const int o0 = ((0 * 8 + ks) * 64 + lane) * 8;
      const int o1 = ((1 * 8 + ks) * 64 + lane) * 8;
      const half8_t bh0 = *(const half8_t*)&bsh[o0];
      const half8_t bl0 = *(const half8_t*)&bsl[o0];
      const half8_t bh1 = *(const half8_t*)&bsh[o1];
      const half8_t bl1 = *(const half8_t*)&bsl[o1];
      qh[0] = __builtin_amdgcn_mfma_f32_16x16x32_f16(ah[ks], bh0, qh[0], 0, 0, 0);
      ql[0] = __builtin_amdgcn_mfma_f32_16x16x32_f16(al[ks], bh0, ql[0], 0, 0, 0);
      ql[0] = __builtin_amdgcn_mfma_f32_16x16x32_f16(ah[ks], bl0, ql[0], 0, 0, 0);
      qh[1] = __builtin_amdgcn_mfma_f32_16x16x32_f16(ah[ks], bh1, qh[1], 0, 0, 0);
      ql[1] = __builtin_amdgcn_mfma_f32_16x16x32_f16(al[ks], bh1, ql[1], 0, 0, 0);
      ql[1] = __builtin_amdgcn_mfma_f32_16x16x32_f16(ah[ks], bl1, ql[1], 0, 0, 0);
    }
    __syncthreads();   // all waves done reading LDS B-chunk
    if (cf < 31) stage_chunk(chs, cls, bsh, bsl, cf + 1, wv, lane);

    // S2: epilogue (covers staging latency)
    float yv[8];
    float cmax[4] = {-1e30f, -1e30f, -1e30f, -1e30f};
#pragma unroll
    for (int c = 0; c < 2; ++c) {
      const int col = cf * 32 + c * 16 + l15;
      const float cq = cbc[c];
      const float fc = (float)col;
#pragma unroll
      for (int g = 0; g < 4; ++g) {
        const float dd = cq + zs[g] - 2.f * (qh[c][g] + ql[c][g]);
        const float lv = -dd;
        if (__builtin_expect(lv > m1[g] + 8.f, 0)) {
          const float f = __expf(m1[g] - lv);
          s1[g] *= f; t1[g] *= f; m1[g] = lv;
        }
        const float e = __expf(lv - m1[g]);
        s1[g] += e;
        t1[g] = __fmaf_rn(e, dd, t1[g]);
        const float y = 2.f * (gc[c * 4 + g] - dd);
        yv[c * 4 + g] = y;
        const bool b1 = (y > v1[g]);
        const bool b2 = (y > v2[g]);
        const bool b3 = (y > v3[g]);
        v3[g] = b2 ? v2[g] : (b3 ? y : v3[g]);
        v2[g] = b1 ? v1[g] : (b2 ? y : v2[g]);
        i2[g] = b1 ? i1[g] : (b2 ? fc : i2[g]);
        v1[g] = b1 ? y : v1[g];
        i1[g] = b1 ? fc : i1[g];
        cmax[g] = fmaxf(cmax[g], y);
      }
    }
#pragma unroll
    for (int mk = 1; mk < 16; mk <<= 1)
#pragma unroll
      for (int g = 0; g < 4; ++g) cmax[g] = fmaxf(cmax[g], __shfl_xor(cmax[g], mk));
    // running-max update (uniform per 16-lane group)
#pragma unroll
    for (int g = 0; g < 4; ++g) {
      if (cmax[g] > mr[g] + THR) {
        s2[g] *= __expf(mr[g] - cmax[g]);
        mr[g] = cmax[g];
      }
    }
    // u = exp(y - mr), transpose via wave-local LDS
#pragma unroll
    for (int c = 0; c < 2; ++c)
#pragma unroll
      for (int g = 0; g < 4; ++g) {
        const float u = __expf(yv[c * 4 + g] - mr[g]);
        s2[g] += u;
        ubuf[wv][lq * 4 + g][c * 16 + l15] = (_Float16)u;
      }
    if (l15 == 0) {
#pragma unroll
      for (int g = 0; g < 4; ++g)
        mrbuf[((size_t)rt * 32 + cf) * 16 + lq * 4 + g] = mr[g];
    }
    const half8_t pa = *(const half8_t*)&ubuf[wv][l15][lq * 8];
    *(half8_t*)&ubig[((size_t)rt * 32 + cf) * 512 + l15 * 32 + lq * 8] = pa;
    if (cf < 31) {
#pragma unroll
      for (int i = 0; i < 8; ++i) gc[i] = gn[i];
      cbc[0] = cbn[0]; cbc[1] = cbn[1];
    }
    __syncthreads();   // stage complete before next S1 reads
  }

  // finalize: merge across the 16-lane group
#pragma unroll
  for (int mk = 1; mk < 16; mk <<= 1) {
#pragma unroll
    for (int g = 0; g < 4; ++g) {
      const float om = __shfl_xor(m1[g], mk);
      const float os = __shfl_xor(s1[g], mk);
      const float ot = __shfl_xor(t1[g], mk);
      pmerge(m1[g], s1[g], t1[g], om, os, ot);
      const float ov1 = __shfl_xor(v1[g], mk);
      const float oi1 = __shfl_xor(i1[g], mk);
      const float ov2 = __shfl_xor(v2[g], mk);
      const float oi2 = __shfl_xor(i2[g], mk);
      const float ov3 = __shfl_xor(v3[g], mk);
      top3_merge(v1[g], i1[g], v2[g], i2[g], v3[g], ov1, oi1, ov2, oi2, ov3);
      s2[g] += __shfl_xor(s2[g], mk);   // mr uniform per group -> plain add
    }
  }
  float klsum = 0.f, cmsum = 0.f;
#pragma unroll
  for (int g = 0; g < 4; ++g) {
    const float commit_row = t1[g] / s1[g];
    const float lse = m1[g] + logf(s1[g]);
    klsum += -commit_row - lse + LOG_SLOTS;
    cmsum += commit_row;
    if (l15 == 0) {
      const int row = rw + lq * 4 + g;
      out[IDX_OFF + row] = i1[g];
      float4 tv; tv.x = v1[g]; tv.y = v2[g]; tv.z = v3[g]; tv.w = i2[g];
      *(float4*)&topw[(size_t)row * 4] = tv;
      normbuf[row] = make_float2(mr[g], 1.f / s2[g]);
    }
  }
  float kw = (l15 == 0) ? klsum : 0.f;
  float cw = (l15 == 0) ? cmsum : 0.f;
#pragma unroll
  for (int mk = 1; mk < 64; mk <<= 1) { kw += __shfl_xor(kw, mk); cw += __shfl_xor(cw, mk); }
  if (lane == 0) {
    atomicAdd(&out[KL_OFF], kw * 0.03125f);
    atomicAdd(&out[CM_OFF], cw * 0.03125f);
  }
}

// k4: PV streaming GEMM, z_q^T = V^T @ u (per-chunk rescale by exp(mr_cf - mr_fin)), no LDS/barriers
__global__ __launch_bounds__(256) __attribute__((amdgpu_waves_per_eu(4, 4)))
void k4_pv(const _Float16* __restrict__ ubig, const float* __restrict__ mrbuf,
           const float2* __restrict__ normbuf, const _Float16* __restrict__ pvs,
           float* __restrict__ out) {
  const int t = threadIdx.x, wv = t >> 6, lane = t & 63, l15 = lane & 15, lq = lane >> 4;
  const int rt = blockIdx.x * 4 + wv;
  const int r0 = rt * 16;
  const int b = r0 >> 11, w0 = r0 & 2047;
  const float2 nv = normbuf[r0 + l15];
  const float mrfin = nv.x, inv = nv.y;
  v4f pacc[16];
#pragma unroll
  for (int dt = 0; dt < 16; ++dt) pacc[dt] = v4f{0.f, 0.f, 0.f, 0.f};

  float mrc = mrbuf[(size_t)rt * 32 * 16 + l15];
  half8_t pa0 = *(const half8_t*)&ubig[(size_t)rt * 32 * 512 + l15 * 32 + lq * 8];
#pragma unroll 1
  for (int cf = 0; cf < 32; ++cf) {
    float mrn = 0.f; half8_t pan = pa0;
    if (cf < 31) {
      mrn = mrbuf[((size_t)rt * 32 + cf + 1) * 16 + l15];
      pan = *(const half8_t*)&ubig[((size_t)rt * 32 + cf + 1) * 512 + l15 * 32 + lq * 8];
    }
    const float f = __expf(mrc - mrfin);
    half8_t pa;
#pragma unroll
    for (int j = 0; j < 8; ++j) pa[j] = (_Float16)((float)pa0[j] * f);
#pragma unroll
    for (int dt = 0; dt < 16; ++dt) {
      const half8_t pb = *(const half8_t*)&pvs[((size_t)(cf * 16 + dt) * 64 + lane) * 8];
      pacc[dt] = __builtin_amdgcn_mfma_f32_16x16x32_f16(pb, pa, pacc[dt], 0, 0, 0);
    }
    mrc = mrn; pa0 = pan;
  }
#pragma unroll
  for (int dt = 0; dt < 16; ++dt)
#pragma unroll
    for (int g = 0; g < 4; ++g)
      out[((size_t)b * DIMD + dt * 16 + lq * 4 + g) * WW + w0 + l15] = pacc[dt][g] * inv;
}

// fp64 argmax repair for near-tie rows
__global__ void k5_repair(const float* __restrict__ z_e, const float* __restrict__ cb,
                          const float* __restrict__ gum, const float* __restrict__ topw,
                          float* __restrict__ out) {
  const int wv = threadIdx.x >> 6, lane = threadIdx.x & 63;
#pragma unroll 1
  for (int rr = 0; rr < 64; ++rr) {
    const int r = blockIdx.x * 256 + wv * 64 + rr;
    const float4 tw = *(const float4*)&topw[(size_t)r * 4];
    if (tw.x - tw.y >= 0.02f) continue;
    const int b = r >> 11, w = r & 2047;
    double zd[4]; double zq = 0.0;
#pragma unroll
    for (int i = 0; i < 4; ++i) {
      const float zz = z_e[((size_t)b * DIMD + lane + i * 64) * WW + w];
      zd[i] = (double)zz; zq += zd[i] * zd[i];
    }
#pragma unroll
    for (int mk = 1; mk < 64; mk <<= 1) zq += __shfl_xor(zq, mk);
    const int c1 = (int)out[IDX_OFF + r];
    const int c2 = (int)tw.w;
    const bool full = (tw.x - tw.z < 0.02f);
    double bestv = -1e300; int besti = 0;
    const int nc = full ? SLOTS : 2;
    for (int ci = 0; ci < nc; ++ci) {
      const int s = full ? ci : (ci == 0 ? c1 : c2);
      double dot = 0.0, csq = 0.0;
#pragma unroll
      for (int i = 0; i < 4; ++i) {
        const double cv = (double)cb[(size_t)s * DIMD + lane + i * 64];
        dot += zd[i] * cv; csq += cv * cv;
      }
#pragma unroll
      for (int mk = 1; mk < 64; mk <<= 1) { dot += __shfl_xor(dot, mk); csq += __shfl_xor(csq, mk); }
      const double y = 2.0 * ((double)gum[(size_t)r * SLOTS + s] - (csq + zq - 2.0 * dot));
      if (y > bestv || (y == bestv && s < besti)) { bestv = y; besti = s; }
    }
    if (lane == 0) out[IDX_OFF + r] = (float)besti;
  }
}

extern "C" void kernel_launch(void* const* d_in, const int* in_sizes, int n_in,
                              void* d_out, int out_size, void* d_ws, size_t ws_size,
                              hipStream_t stream) {
  const float* z_e = (const float*)d_in[0];
  const float* cb  = (const float*)d_in[1];
  const float* gum = (const float*)d_in[2];
  float* out = (float*)d_out;
  char* ws = (char*)d_ws;
  if (ws_size < WS_NEED) {
    hipMemsetAsync(d_out, 0, (size_t)out_size * sizeof(float), stream);
    return;
  }
  _Float16* chs = (_Float16*)(ws + WS_CH);
  _Float16* cls = (_Float16*)(ws + WS_CL);
  _Float16* pvs = (_Float16*)(ws + WS_PV);
  float* cbsq = (float*)(ws + WS_CBSQ);
  float* topw = (float*)(ws + WS_TOP);
  float* mrbuf = (float*)(ws + WS_MR);
  float2* normbuf = (float2*)(ws + WS_NORM);
  _Float16* ubig = (_Float16*)(ws + WS_U);
  k0_zero<<<1, 1, 0, stream>>>(out);
  k2_pack<<<128, 256, 0, stream>>>(cb, chs, cls, pvs, cbsq);
  k3_main<<<1024, 256, 0, stream>>>(z_e, gum, chs, cls, cbsq, ubig, mrbuf, normbuf, topw, out);
  k4_pv<<<1024, 256, 0, stream>>>(ubig, mrbuf, normbuf, pvs, out);
  k5_repair<<<256, 256, 0, stream>>>(z_e, cb, gum, topw, out);
}

// Round 6
// 765.362 us; speedup vs baseline: 1.1282x; 1.1282x over previous
//
#include <hip/hip_runtime.h>

#define BSZ 32
#define DIMD 256
#define WW 2048
#define SLOTS 1024
#define NROWS (BSZ*WW)
#define LOG_SLOTS 6.931471805599453f
#define THR 4.0f

#define ZQ_N (BSZ*DIMD*WW)
#define IDX_OFF ZQ_N
#define KL_OFF (ZQ_N + NROWS)
#define CM_OFF (KL_OFF + 1)

// workspace byte offsets
#define WS_CH   0u
#define WS_CL   524288u
#define WS_PV   1048576u
#define WS_CBSQ 1572864u
#define WS_TOP  1576960u
#define WS_MR   2625536u
#define WS_NORM 11014144u
#define WS_U    11538432u
#define WS_NEED (11538432ull + 134217728ull)

typedef _Float16 half2_t __attribute__((ext_vector_type(2)));
typedef _Float16 half8_t __attribute__((ext_vector_type(8)));
typedef float v4f __attribute__((ext_vector_type(4)));

__device__ __forceinline__ void pmerge(float& m, float& s, float& t, float om, float os, float ot) {
  float M = fmaxf(m, om);
  float ea = __expf(m - M), eb = __expf(om - M);
  s = s * ea + os * eb;
  t = t * ea + ot * eb;
  m = M;
}

__device__ __forceinline__ void top3_merge(float& v1, float& i1, float& v2, float& i2, float& v3,
                                           float ov1, float oi1, float ov2, float oi2, float ov3) {
  bool sw = (ov1 > v1) || (ov1 == v1 && oi1 < i1);
  float a1v = sw ? ov1 : v1, a1i = sw ? oi1 : i1;
  float a2v = sw ? ov2 : v2, a2i = sw ? oi2 : i2;
  float a3v = sw ? ov3 : v3;
  float b1v = sw ? v1 : ov1, b1i = sw ? i1 : oi1;
  float b2v = sw ? v2 : ov2;
  bool a2w = (a2v > b1v) || (a2v == b1v && a2i < b1i);
  v1 = a1v; i1 = a1i;
  v2 = a2w ? a2v : b1v;
  i2 = a2w ? a2i : b1i;
  v3 = a2w ? fmaxf(a3v, b1v) : fmaxf(a2v, b2v);
}

__global__ void k0_zero(float* out) { out[KL_OFF] = 0.f; out[CM_OFF] = 0.f; }

// pack codebook: chs/cls = fp16 hi/lo B-fragment stream for QK^T (chunk-contiguous 16KB tiles);
// pvs = fp16 A-fragment stream for PV; cbsq in fp64->fp32
__global__ void k2_pack(const float* __restrict__ cb, _Float16* __restrict__ chs,
                        _Float16* __restrict__ cls, _Float16* __restrict__ pvs,
                        float* __restrict__ cbsq) {
  const int tid = blockIdx.x * 256 + threadIdx.x;
  if (tid < 32768) {
    const int lane = tid & 63;
    {
      const int ks = (tid >> 6) & 7, sblk = tid >> 9;
      const int col = sblk * 16 + (lane & 15);
      const int k0 = ks * 32 + (lane >> 4) * 8;
      half8_t vh, vl;
#pragma unroll
      for (int j = 0; j < 8; ++j) {
        const float v = cb[(size_t)col * DIMD + k0 + j];
        const _Float16 h = (_Float16)v;
        vh[j] = h;
        vl[j] = (_Float16)(v - (float)h);
      }
      *(half8_t*)&chs[(size_t)tid * 8] = vh;
      *(half8_t*)&cls[(size_t)tid * 8] = vl;
    }
    {
      const int idx = tid >> 6;
      const int cf = idx >> 4, dt = idx & 15;
      const int d = dt * 16 + (lane & 15);
      const int s0 = cf * 32 + (lane >> 4) * 8;
      half8_t vp;
#pragma unroll
      for (int j = 0; j < 8; ++j)
        vp[j] = (_Float16)cb[(size_t)(s0 + j) * DIMD + d];
      *(half8_t*)&pvs[(size_t)tid * 8] = vp;
    }
  }
  if (tid < SLOTS) {
    double a = 0.0;
    for (int i = 0; i < DIMD; ++i) { const double v = (double)cb[(size_t)tid * DIMD + i]; a += v * v; }
    cbsq[tid] = (float)a;
  }
}

// async stage one 16KB chunk (hi+lo) of codebook fragments into LDS (linear, global_load_lds)
__device__ __forceinline__ void stage_chunk(const _Float16* __restrict__ chs,
                                            const _Float16* __restrict__ cls,
                                            _Float16* bsh, _Float16* bsl,
                                            int cf, int wv, int lane) {
  const size_t gbase = (size_t)cf * 8192 + wv * 2048 + lane * 8;
#pragma unroll
  for (int i = 0; i < 4; ++i) {
    __builtin_amdgcn_global_load_lds(
        (const __attribute__((address_space(1))) void*)(chs + gbase + i * 512),
        (__attribute__((address_space(3))) void*)(bsh + wv * 2048 + i * 512), 16, 0, 0);
    __builtin_amdgcn_global_load_lds(
        (const __attribute__((address_space(1))) void*)(cls + gbase + i * 512),
        (__attribute__((address_space(3))) void*)(bsl + wv * 2048 + i * 512), 16, 0, 0);
  }
}

// k3: QK^T (fp16-split MFMA, B staged in LDS) + online probs stats + top3 + u write (fp16)
// waves_per_eu(3,3): cap = 512/3 = 170 regs >= ~140 demand -> spill-free, 12 waves/CU (m97's point)
__global__ __launch_bounds__(256) __attribute__((amdgpu_waves_per_eu(3, 3)))
void k3_main(const float* __restrict__ z_e, const float* __restrict__ gum,
             const _Float16* __restrict__ chs, const _Float16* __restrict__ cls,
             const float* __restrict__ cbsq, _Float16* __restrict__ ubig,
             float* __restrict__ mrbuf, float2* __restrict__ normbuf,
             float* __restrict__ topw, float* __restrict__ out) {
  __shared__ _Float16 bsh[8192];
  __shared__ _Float16 bsl[8192];
  __shared__ _Float16 ubuf[4][16][44];   // 88B row stride: transpose read conflict-free (R5: 0 conflicts)

  const int t = threadIdx.x, wv = t >> 6, lane = t & 63, l15 = lane & 15, lq = lane >> 4;
  const int r0 = blockIdx.x * 64;
  const int rw = r0 + wv * 16;
  const int rt = blockIdx.x * 4 + wv;
  const int b = r0 >> 11;
  const int w0 = rw & 2047;

  stage_chunk(chs, cls, bsh, bsl, 0, wv, lane);

  // z fragments to registers (fp16 hi/lo split)
  const float* zbase = z_e + (size_t)b * DIMD * WW + w0 + l15;
  half8_t ah[8], al[8];
  float zacc = 0.f;
#pragma unroll
  for (int ks = 0; ks < 8; ++ks) {
#pragma unroll
    for (int j = 0; j < 8; ++j) {
      const float v = zbase[(size_t)(ks * 32 + lq * 8 + j) * WW];
      zacc += v * v;
      const _Float16 h = (_Float16)v;
      ah[ks][j] = h;
      al[ks][j] = (_Float16)(v - (float)h);
    }
  }
  zacc += __shfl_xor(zacc, 16);
  zacc += __shfl_xor(zacc, 32);
  float zs[4];
#pragma unroll
  for (int g = 0; g < 4; ++g) zs[g] = __shfl(zacc, lq * 4 + g);

  float m1[4], s1[4], t1[4], v1[4], v2[4], v3[4], i1[4], i2[4], s2[4], mr[4];
#pragma unroll
  for (int g = 0; g < 4; ++g) {
    m1[g] = -1e30f; s1[g] = 0.f; t1[g] = 0.f;
    v1[g] = -1e30f; v2[g] = -1e30f; v3[g] = -1e30f; i1[g] = 0.f; i2[g] = 0.f;
    s2[g] = 0.f; mr[g] = -1e30f;
  }

  const float* gbase = gum + (size_t)rw * SLOTS;
  float gc[8], cbc[2];
#pragma unroll
  for (int c = 0; c < 2; ++c) {
    cbc[c] = cbsq[c * 16 + l15];
#pragma unroll
    for (int g = 0; g < 4; ++g)
      gc[c * 4 + g] = gbase[(size_t)(lq * 4 + g) * SLOTS + c * 16 + l15];
  }

  __syncthreads();   // stage(0) complete

#pragma unroll 1
  for (int cf = 0; cf < 32; ++cf) {
    // S1: gum/cbsq prefetch for next chunk, then MFMAs on staged B
    float gn[8], cbn[2];
    if (cf < 31) {
#pragma unroll
      for (int c = 0; c < 2; ++c) {
        cbn[c] = cbsq[(cf + 1) * 32 + c * 16 + l15];
#pragma unroll
        for (int g = 0; g < 4; ++g)
          gn[c * 4 + g] = gbase[(size_t)(lq * 4 + g) * SLOTS + (cf + 1) * 32 + c * 16 + l15];
      }
    }
    v4f qh[2], ql[2];
    qh[0] = v4f{0.f, 0.f, 0.f, 0.f}; qh[1] = v4f{0.f, 0.f, 0.f, 0.f};
    ql[0] = v4f{0.f, 0.f, 0.f, 0.f}; ql[1] = v4f{0.f, 0.f, 0.f, 0.f};
#pragma unroll
    for (int ks = 0; ks < 8; ++ks) {
      const int o0 = ((0 * 8 + ks) * 64 + lane) * 8;
      const int o1 = ((1 * 8 + ks) * 64 + lane) * 8;
      const half8_t bh0 = *(const half8_t*)&bsh[o0];
      const half8_t bl0 = *(const half8_t*)&bsl[o0];
      const half8_t bh1 = *(const half8_t*)&bsh[o1];
      const half8_t bl1 = *(const half8_t*)&bsl[o1];
      qh[0] = __builtin_amdgcn_mfma_f32_16x16x32_f16(ah[ks], bh0, qh[0], 0, 0, 0);
      ql[0] = __builtin_amdgcn_mfma_f32_16x16x32_f16(al[ks], bh0, ql[0], 0, 0, 0);
      ql[0] = __builtin_amdgcn_mfma_f32_16x16x32_f16(ah[ks], bl0, ql[0], 0, 0, 0);
      qh[1] = __builtin_amdgcn_mfma_f32_16x16x32_f16(ah[ks], bh1, qh[1], 0, 0, 0);
      ql[1] = __builtin_amdgcn_mfma_f32_16x16x32_f16(al[ks], bh1, ql[1], 0, 0, 0);
      ql[1] = __builtin_amdgcn_mfma_f32_16x16x32_f16(ah[ks], bl1, ql[1], 0, 0, 0);
    }
    __syncthreads();   // all waves done reading LDS B-chunk
    if (cf < 31) stage_chunk(chs, cls, bsh, bsl, cf + 1, wv, lane);

    // S2: epilogue (covers staging latency)
    float yv[8];
    float cmax[4] = {-1e30f, -1e30f, -1e30f, -1e30f};
#pragma unroll
    for (int c = 0; c < 2; ++c) {
      const int col = cf * 32 + c * 16 + l15;
      const float cq = cbc[c];
      const float fc = (float)col;
#pragma unroll
      for (int g = 0; g < 4; ++g) {
        const float dd = cq + zs[g] - 2.f * (qh[c][g] + ql[c][g]);
        const float lv = -dd;
        if (__builtin_expect(lv > m1[g] + 8.f, 0)) {
          const float f = __expf(m1[g] - lv);
          s1[g] *= f; t1[g] *= f; m1[g] = lv;
        }
        const float e = __expf(lv - m1[g]);
        s1[g] += e;
        t1[g] = __fmaf_rn(e, dd, t1[g]);
        const float y = 2.f * (gc[c * 4 + g] - dd);
        yv[c * 4 + g] = y;
        const bool b1 = (y > v1[g]);
        const bool b2 = (y > v2[g]);
        const bool b3 = (y > v3[g]);
        v3[g] = b2 ? v2[g] : (b3 ? y : v3[g]);
        v2[g] = b1 ? v1[g] : (b2 ? y : v2[g]);
        i2[g] = b1 ? i1[g] : (b2 ? fc : i2[g]);
        v1[g] = b1 ? y : v1[g];
        i1[g] = b1 ? fc : i1[g];
        cmax[g] = fmaxf(cmax[g], y);
      }
    }
#pragma unroll
    for (int mk = 1; mk < 16; mk <<= 1)
#pragma unroll
      for (int g = 0; g < 4; ++g) cmax[g] = fmaxf(cmax[g], __shfl_xor(cmax[g], mk));
    // running-max update (uniform per 16-lane group)
#pragma unroll
    for (int g = 0; g < 4; ++g) {
      if (cmax[g] > mr[g] + THR) {
        s2[g] *= __expf(mr[g] - cmax[g]);
        mr[g] = cmax[g];
      }
    }
    // u = exp(y - mr), transpose via wave-local LDS
#pragma unroll
    for (int c = 0; c < 2; ++c)
#pragma unroll
      for (int g = 0; g < 4; ++g) {
        const float u = __expf(yv[c * 4 + g] - mr[g]);
        s2[g] += u;
        ubuf[wv][lq * 4 + g][c * 16 + l15] = (_Float16)u;
      }
    if (l15 == 0) {
#pragma unroll
      for (int g = 0; g < 4; ++g)
        mrbuf[((size_t)rt * 32 + cf) * 16 + lq * 4 + g] = mr[g];
    }
    const half8_t pa = *(const half8_t*)&ubuf[wv][l15][lq * 8];
    *(half8_t*)&ubig[((size_t)rt * 32 + cf) * 512 + l15 * 32 + lq * 8] = pa;
    if (cf < 31) {
#pragma unroll
      for (int i = 0; i < 8; ++i) gc[i] = gn[i];
      cbc[0] = cbn[0]; cbc[1] = cbn[1];
    }
    __syncthreads();   // stage complete before next S1 reads
  }

  // finalize: merge across the 16-lane group
#pragma unroll
  for (int mk = 1; mk < 16; mk <<= 1) {
#pragma unroll
    for (int g = 0; g < 4; ++g) {
      const float om = __shfl_xor(m1[g], mk);
      const float os = __shfl_xor(s1[g], mk);
      const float ot = __shfl_xor(t1[g], mk);
      pmerge(m1[g], s1[g], t1[g], om, os, ot);
      const float ov1 = __shfl_xor(v1[g], mk);
      const float oi1 = __shfl_xor(i1[g], mk);
      const float ov2 = __shfl_xor(v2[g], mk);
      const float oi2 = __shfl_xor(i2[g], mk);
      const float ov3 = __shfl_xor(v3[g], mk);
      top3_merge(v1[g], i1[g], v2[g], i2[g], v3[g], ov1, oi1, ov2, oi2, ov3);
      s2[g] += __shfl_xor(s2[g], mk);   // mr uniform per group -> plain add
    }
  }
  float klsum = 0.f, cmsum = 0.f;
#pragma unroll
  for (int g = 0; g < 4; ++g) {
    const float commit_row = t1[g] / s1[g];
    const float lse = m1[g] + logf(s1[g]);
    klsum += -commit_row - lse + LOG_SLOTS;
    cmsum += commit_row;
    if (l15 == 0) {
      const int row = rw + lq * 4 + g;
      out[IDX_OFF + row] = i1[g];
      float4 tv; tv.x = v1[g]; tv.y = v2[g]; tv.z = v3[g]; tv.w = i2[g];
      *(float4*)&topw[(size_t)row * 4] = tv;
      normbuf[row] = make_float2(mr[g], 1.f / s2[g]);
    }
  }
  float kw = (l15 == 0) ? klsum : 0.f;
  float cw = (l15 == 0) ? cmsum : 0.f;
#pragma unroll
  for (int mk = 1; mk < 64; mk <<= 1) { kw += __shfl_xor(kw, mk); cw += __shfl_xor(cw, mk); }
  if (lane == 0) {
    atomicAdd(&out[KL_OFF], kw * 0.03125f);
    atomicAdd(&out[CM_OFF], cw * 0.03125f);
  }
}

// k4: PV streaming GEMM, z_q^T = V^T @ u (per-chunk rescale by exp(mr_cf - mr_fin)), no LDS/barriers
__global__ __launch_bounds__(256) __attribute__((amdgpu_waves_per_eu(3, 3)))
void k4_pv(const _Float16* __restrict__ ubig, const float* __restrict__ mrbuf,
           const float2* __restrict__ normbuf, const _Float16* __restrict__ pvs,
           float* __restrict__ out) {
  const int t = threadIdx.x, wv = t >> 6, lane = t & 63, l15 = lane & 15, lq = lane >> 4;
  const int rt = blockIdx.x * 4 + wv;
  const int r0 = rt * 16;
  const int b = r0 >> 11, w0 = r0 & 2047;
  const float2 nv = normbuf[r0 + l15];
  const float mrfin = nv.x, inv = nv.y;
  v4f pacc[16];
#pragma unroll
  for (int dt = 0; dt < 16; ++dt) pacc[dt] = v4f{0.f, 0.f, 0.f, 0.f};

  float mrc = mrbuf[(size_t)rt * 32 * 16 + l15];
  half8_t pa0 = *(const half8_t*)&ubig[(size_t)rt * 32 * 512 + l15 * 32 + lq * 8];
#pragma unroll 1
  for (int cf = 0; cf < 32; ++cf) {
    float mrn = 0.f; half8_t pan = pa0;
    if (cf < 31) {
      mrn = mrbuf[((size_t)rt * 32 + cf + 1) * 16 + l15];
      pan = *(const half8_t*)&ubig[((size_t)rt * 32 + cf + 1) * 512 + l15 * 32 + lq * 8];
    }
    const float f = __expf(mrc - mrfin);
    half8_t pa;
#pragma unroll
    for (int j = 0; j < 8; ++j) pa[j] = (_Float16)((float)pa0[j] * f);
#pragma unroll
    for (int dt = 0; dt < 16; ++dt) {
      const half8_t pb = *(const half8_t*)&pvs[((size_t)(cf * 16 + dt) * 64 + lane) * 8];
      pacc[dt] = __builtin_amdgcn_mfma_f32_16x16x32_f16(pb, pa, pacc[dt], 0, 0, 0);
    }
    mrc = mrn; pa0 = pan;
  }
#pragma unroll
  for (int dt = 0; dt < 16; ++dt)
#pragma unroll
    for (int g = 0; g < 4; ++g)
      out[((size_t)b * DIMD + dt * 16 + lq * 4 + g) * WW + w0 + l15] = pacc[dt][g] * inv;
}

// fp64 argmax repair for near-tie rows
__global__ void k5_repair(const float* __restrict__ z_e, const float* __restrict__ cb,
                          const float* __restrict__ gum, const float* __restrict__ topw,
                          float* __restrict__ out) {
  const int wv = threadIdx.x >> 6, lane = threadIdx.x & 63;
#pragma unroll 1
  for (int rr = 0; rr < 64; ++rr) {
    const int r = blockIdx.x * 256 + wv * 64 + rr;
    const float4 tw = *(const float4*)&topw[(size_t)r * 4];
    if (tw.x - tw.y >= 0.02f) continue;
    const int b = r >> 11, w = r & 2047;
    double zd[4]; double zq = 0.0;
#pragma unroll
    for (int i = 0; i < 4; ++i) {
      const float zz = z_e[((size_t)b * DIMD + lane + i * 64) * WW + w];
      zd[i] = (double)zz; zq += zd[i] * zd[i];
    }
#pragma unroll
    for (int mk = 1; mk < 64; mk <<= 1) zq += __shfl_xor(zq, mk);
    const int c1 = (int)out[IDX_OFF + r];
    const int c2 = (int)tw.w;
    const bool full = (tw.x - tw.z < 0.02f);
    double bestv = -1e300; int besti = 0;
    const int nc = full ? SLOTS : 2;
    for (int ci = 0; ci < nc; ++ci) {
      const int s = full ? ci : (ci == 0 ? c1 : c2);
      double dot = 0.0, csq = 0.0;
#pragma unroll
      for (int i = 0; i < 4; ++i) {
        const double cv = (double)cb[(size_t)s * DIMD + lane + i * 64];
        dot += zd[i] * cv; csq += cv * cv;
      }
#pragma unroll
      for (int mk = 1; mk < 64; mk <<= 1) { dot += __shfl_xor(dot, mk); csq += __shfl_xor(csq, mk); }
      const double y = 2.0 * ((double)gum[(size_t)r * SLOTS + s] - (csq + zq - 2.0 * dot));
      if (y > bestv || (y == bestv && s < besti)) { bestv = y; besti = s; }
    }
    if (lane == 0) out[IDX_OFF + r] = (float)besti;
  }
}

extern "C" void kernel_launch(void* const* d_in, const int* in_sizes, int n_in,
                              void* d_out, int out_size, void* d_ws, size_t ws_size,
                              hipStream_t stream) {
  const float* z_e = (const float*)d_in[0];
  const float* cb  = (const float*)d_in[1];
  const float* gum = (const float*)d_in[2];
  float* out = (float*)d_out;
  char* ws = (char*)d_ws;
  if (ws_size < WS_NEED) {
    hipMemsetAsync(d_out, 0, (size_t)out_size * sizeof(float), stream);
    return;
  }
  _Float16* chs = (_Float16*)(ws + WS_CH);
  _Float16* cls = (_Float16*)(ws + WS_CL);
  _Float16* pvs = (_Float16*)(ws + WS_PV);
  float* cbsq = (float*)(ws + WS_CBSQ);
  float* topw = (float*)(ws + WS_TOP);
  float* mrbuf = (float*)(ws + WS_MR);
  float2* normbuf = (float2*)(ws + WS_NORM);
  _Float16* ubig = (_Float16*)(ws + WS_U);
  k0_zero<<<1, 1, 0, stream>>>(out);
  k2_pack<<<128, 256, 0, stream>>>(cb, chs, cls, pvs, cbsq);
  k3_main<<<1024, 256, 0, stream>>>(z_e, gum, chs, cls, cbsq, ubig, mrbuf, normbuf, topw, out);
  k4_pv<<<1024, 256, 0, stream>>>(ubig, mrbuf, normbuf, pvs, out);
  k5_repair<<<256, 256, 0, stream>>>(z_e, cb, gum, topw, out);
}

// Round 7
// 465.138 us; speedup vs baseline: 1.8564x; 1.6455x over previous
//
#include <hip/hip_runtime.h>

#define BSZ 32
#define DIMD 256
#define WW 2048
#define SLOTS 1024
#define NROWS (BSZ*WW)
#define LOG_SLOTS 6.931471805599453f
#define THR 4.0f

#define ZQ_N (BSZ*DIMD*WW)
#define IDX_OFF ZQ_N
#define KL_OFF (ZQ_N + NROWS)
#define CM_OFF (KL_OFF + 1)

// workspace byte offsets
#define WS_CH   0u
#define WS_CL   524288u
#define WS_PV   1048576u
#define WS_CBSQ 1572864u
#define WS_TOP  1576960u
#define WS_MR   2625536u
#define WS_NORM 11014144u
#define WS_U    11538432u
#define WS_NEED (11538432ull + 134217728ull)

typedef _Float16 half2_t __attribute__((ext_vector_type(2)));
typedef _Float16 half8_t __attribute__((ext_vector_type(8)));
typedef float v4f __attribute__((ext_vector_type(4)));

__device__ __forceinline__ void pmerge(float& m, float& s, float& t, float om, float os, float ot) {
  float M = fmaxf(m, om);
  float ea = __expf(m - M), eb = __expf(om - M);
  s = s * ea + os * eb;
  t = t * ea + ot * eb;
  m = M;
}

__device__ __forceinline__ void top3_merge(float& v1, float& i1, float& v2, float& i2, float& v3,
                                           float ov1, float oi1, float ov2, float oi2, float ov3) {
  bool sw = (ov1 > v1) || (ov1 == v1 && oi1 < i1);
  float a1v = sw ? ov1 : v1, a1i = sw ? oi1 : i1;
  float a2v = sw ? ov2 : v2, a2i = sw ? oi2 : i2;
  float a3v = sw ? ov3 : v3;
  float b1v = sw ? v1 : ov1, b1i = sw ? i1 : oi1;
  float b2v = sw ? v2 : ov2;
  bool a2w = (a2v > b1v) || (a2v == b1v && a2i < b1i);
  v1 = a1v; i1 = a1i;
  v2 = a2w ? a2v : b1v;
  i2 = a2w ? a2i : b1i;
  v3 = a2w ? fmaxf(a3v, b1v) : fmaxf(a2v, b2v);
}

__global__ void k0_zero(float* out) { out[KL_OFF] = 0.f; out[CM_OFF] = 0.f; }

// pack codebook: chs/cls = fp16 hi/lo B-fragment stream for QK^T (chunk-contiguous 16KB tiles);
// pvs = fp16 A-fragment stream for PV; cbsq in fp64->fp32
__global__ void k2_pack(const float* __restrict__ cb, _Float16* __restrict__ chs,
                        _Float16* __restrict__ cls, _Float16* __restrict__ pvs,
                        float* __restrict__ cbsq) {
  const int tid = blockIdx.x * 256 + threadIdx.x;
  if (tid < 32768) {
    const int lane = tid & 63;
    {
      const int ks = (tid >> 6) & 7, sblk = tid >> 9;
      const int col = sblk * 16 + (lane & 15);
      const int k0 = ks * 32 + (lane >> 4) * 8;
      half8_t vh, vl;
#pragma unroll
      for (int j = 0; j < 8; ++j) {
        const float v = cb[(size_t)col * DIMD + k0 + j];
        const _Float16 h = (_Float16)v;
        vh[j] = h;
        vl[j] = (_Float16)(v - (float)h);
      }
      *(half8_t*)&chs[(size_t)tid * 8] = vh;
      *(half8_t*)&cls[(size_t)tid * 8] = vl;
    }
    {
      const int idx = tid >> 6;
      const int cf = idx >> 4, dt = idx & 15;
      const int d = dt * 16 + (lane & 15);
      const int s0 = cf * 32 + (lane >> 4) * 8;
      half8_t vp;
#pragma unroll
      for (int j = 0; j < 8; ++j)
        vp[j] = (_Float16)cb[(size_t)(s0 + j) * DIMD + d];
      *(half8_t*)&pvs[(size_t)tid * 8] = vp;
    }
  }
  if (tid < SLOTS) {
    double a = 0.0;
    for (int i = 0; i < DIMD; ++i) { const double v = (double)cb[(size_t)tid * DIMD + i]; a += v * v; }
    cbsq[tid] = (float)a;
  }
}

// async stage one 16KB chunk (hi+lo) of codebook fragments into LDS (linear, global_load_lds)
__device__ __forceinline__ void stage_chunk(const _Float16* __restrict__ chs,
                                            const _Float16* __restrict__ cls,
                                            _Float16* bsh, _Float16* bsl,
                                            int cf, int wv, int lane) {
  const size_t gbase = (size_t)cf * 8192 + wv * 2048 + lane * 8;
#pragma unroll
  for (int i = 0; i < 4; ++i) {
    __builtin_amdgcn_global_load_lds(
        (const __attribute__((address_space(1))) void*)(chs + gbase + i * 512),
        (__attribute__((address_space(3))) void*)(bsh + wv * 2048 + i * 512), 16, 0, 0);
    __builtin_amdgcn_global_load_lds(
        (const __attribute__((address_space(1))) void*)(cls + gbase + i * 512),
        (__attribute__((address_space(3))) void*)(bsl + wv * 2048 + i * 512), 16, 0, 0);
  }
}

// k3: QK^T (fp16-split MFMA, B double-buffered in LDS) + online probs stats + top3 + u write.
// (2,2) is the verified spill-free point (R4); all latency ops issued at iteration top with
// a full iteration of slack; ONE barrier per chunk.
__global__ __launch_bounds__(256) __attribute__((amdgpu_waves_per_eu(2, 2)))
void k3_main(const float* __restrict__ z_e, const float* __restrict__ gum,
             const _Float16* __restrict__ chs, const _Float16* __restrict__ cls,
             const float* __restrict__ cbsq, _Float16* __restrict__ ubig,
             float* __restrict__ mrbuf, float2* __restrict__ normbuf,
             float* __restrict__ topw, float* __restrict__ out) {
  __shared__ _Float16 bsh[2][8192];      // double-buffered B hi
  __shared__ _Float16 bsl[2][8192];      // double-buffered B lo
  __shared__ _Float16 ubuf[4][16][44];   // 88B row stride: transpose read conflict-free (R5: 0 conflicts)

  const int t = threadIdx.x, wv = t >> 6, lane = t & 63, l15 = lane & 15, lq = lane >> 4;
  const int r0 = blockIdx.x * 64;
  const int rw = r0 + wv * 16;
  const int rt = blockIdx.x * 4 + wv;
  const int b = r0 >> 11;
  const int w0 = rw & 2047;

  stage_chunk(chs, cls, bsh[0], bsl[0], 0, wv, lane);

  // z fragments to registers (fp16 hi/lo split)
  const float* zbase = z_e + (size_t)b * DIMD * WW + w0 + l15;
  half8_t ah[8], al[8];
  float zacc = 0.f;
#pragma unroll
  for (int ks = 0; ks < 8; ++ks) {
#pragma unroll
    for (int j = 0; j < 8; ++j) {
      const float v = zbase[(size_t)(ks * 32 + lq * 8 + j) * WW];
      zacc += v * v;
      const _Float16 h = (_Float16)v;
      ah[ks][j] = h;
      al[ks][j] = (_Float16)(v - (float)h);
    }
  }
  zacc += __shfl_xor(zacc, 16);
  zacc += __shfl_xor(zacc, 32);
  float zs[4];
#pragma unroll
  for (int g = 0; g < 4; ++g) zs[g] = __shfl(zacc, lq * 4 + g);

  float m1[4], s1[4], t1[4], v1[4], v2[4], v3[4], i1[4], i2[4], s2[4], mr[4];
#pragma unroll
  for (int g = 0; g < 4; ++g) {
    m1[g] = -1e30f; s1[g] = 0.f; t1[g] = 0.f;
    v1[g] = -1e30f; v2[g] = -1e30f; v3[g] = -1e30f; i1[g] = 0.f; i2[g] = 0.f;
    s2[g] = 0.f; mr[g] = -1e30f;
  }

  const float* gbase = gum + (size_t)rw * SLOTS;
  float gc[8], cbc[2];
#pragma unroll
  for (int c = 0; c < 2; ++c) {
    cbc[c] = cbsq[c * 16 + l15];
#pragma unroll
    for (int g = 0; g < 4; ++g)
      gc[c * 4 + g] = gbase[(size_t)(lq * 4 + g) * SLOTS + c * 16 + l15];
  }

  __syncthreads();   // stage(0) complete & visible

#pragma unroll 1
  for (int cf = 0; cf < 32; ++cf) {
    const int cb_ = cf & 1;
    // top of iteration: issue next-chunk stage (into the buffer released by the
    // previous barrier) + next-chunk gum/cbsq prefetch. Drain point is this
    // iteration's END barrier -> a full iteration of latency slack.
    float gn[8], cbn[2];
    if (cf < 31) {
      stage_chunk(chs, cls, bsh[cb_ ^ 1], bsl[cb_ ^ 1], cf + 1, wv, lane);
#pragma unroll
      for (int c = 0; c < 2; ++c) {
        cbn[c] = cbsq[(cf + 1) * 32 + c * 16 + l15];
#pragma unroll
        for (int g = 0; g < 4; ++g)
          gn[c * 4 + g] = gbase[(size_t)(lq * 4 + g) * SLOTS + (cf + 1) * 32 + c * 16 + l15];
      }
    }
    // MFMA phase on current staged buffer
    v4f qh[2], ql[2];
    qh[0] = v4f{0.f, 0.f, 0.f, 0.f}; qh[1] = v4f{0.f, 0.f, 0.f, 0.f};
    ql[0] = v4f{0.f, 0.f, 0.f, 0.f}; ql[1] = v4f{0.f, 0.f, 0.f, 0.f};
#pragma unroll
    for (int ks = 0; ks < 8; ++ks) {
      const int o0 = ((0 * 8 + ks) * 64 + lane) * 8;
      const int o1 = ((1 * 8 + ks) * 64 + lane) * 8;
      const half8_t bh0 = *(const half8_t*)&bsh[cb_][o0];
      const half8_t bl0 = *(const half8_t*)&bsl[cb_][o0];
      const half8_t bh1 = *(const half8_t*)&bsh[cb_][o1];
      const half8_t bl1 = *(const half8_t*)&bsl[cb_][o1];
      qh[0] = __builtin_amdgcn_mfma_f32_16x16x32_f16(ah[ks], bh0, qh[0], 0, 0, 0);
      ql[0] = __builtin_amdgcn_mfma_f32_16x16x32_f16(al[ks], bh0, ql[0], 0, 0, 0);
      ql[0] = __builtin_amdgcn_mfma_f32_16x16x32_f16(ah[ks], bl0, ql[0], 0, 0, 0);
      qh[1] = __builtin_amdgcn_mfma_f32_16x16x32_f16(ah[ks], bh1, qh[1], 0, 0, 0);
      ql[1] = __builtin_amdgcn_mfma_f32_16x16x32_f16(al[ks], bh1, ql[1], 0, 0, 0);
      ql[1] = __builtin_amdgcn_mfma_f32_16x16x32_f16(ah[ks], bl1, ql[1], 0, 0, 0);
    }

    // epilogue: distances, probs stats, top3, u
    float yv[8];
    float cmax[4] = {-1e30f, -1e30f, -1e30f, -1e30f};
#pragma unroll
    for (int c = 0; c < 2; ++c) {
      const int col = cf * 32 + c * 16 + l15;
      const float cq = cbc[c];
      const float fc = (float)col;
#pragma unroll
      for (int g = 0; g < 4; ++g) {
        const float dd = cq + zs[g] - 2.f * (qh[c][g] + ql[c][g]);
        const float lv = -dd;
        if (__builtin_expect(lv > m1[g] + 8.f, 0)) {
          const float f = __expf(m1[g] - lv);
          s1[g] *= f; t1[g] *= f; m1[g] = lv;
        }
        const float e = __expf(lv - m1[g]);
        s1[g] += e;
        t1[g] = __fmaf_rn(e, dd, t1[g]);
        const float y = 2.f * (gc[c * 4 + g] - dd);
        yv[c * 4 + g] = y;
        const bool b1 = (y > v1[g]);
        const bool b2 = (y > v2[g]);
        const bool b3 = (y > v3[g]);
        v3[g] = b2 ? v2[g] : (b3 ? y : v3[g]);
        v2[g] = b1 ? v1[g] : (b2 ? y : v2[g]);
        i2[g] = b1 ? i1[g] : (b2 ? fc : i2[g]);
        v1[g] = b1 ? y : v1[g];
        i1[g] = b1 ? fc : i1[g];
        cmax[g] = fmaxf(cmax[g], y);
      }
    }
#pragma unroll
    for (int mk = 1; mk < 16; mk <<= 1)
#pragma unroll
      for (int g = 0; g < 4; ++g) cmax[g] = fmaxf(cmax[g], __shfl_xor(cmax[g], mk));
    // running-max update (uniform per 16-lane group)
#pragma unroll
    for (int g = 0; g < 4; ++g) {
      if (cmax[g] > mr[g] + THR) {
        s2[g] *= __expf(mr[g] - cmax[g]);
        mr[g] = cmax[g];
      }
    }
    // u = exp(y - mr), transpose via wave-local LDS
#pragma unroll
    for (int c = 0; c < 2; ++c)
#pragma unroll
      for (int g = 0; g < 4; ++g) {
        const float u = __expf(yv[c * 4 + g] - mr[g]);
        s2[g] += u;
        ubuf[wv][lq * 4 + g][c * 16 + l15] = (_Float16)u;
      }
    if (l15 == 0) {
#pragma unroll
      for (int g = 0; g < 4; ++g)
        mrbuf[((size_t)rt * 32 + cf) * 16 + lq * 4 + g] = mr[g];
    }
    const half8_t pa = *(const half8_t*)&ubuf[wv][l15][lq * 8];
    *(half8_t*)&ubig[((size_t)rt * 32 + cf) * 512 + l15 * 32 + lq * 8] = pa;
    if (cf < 31) {
#pragma unroll
      for (int i = 0; i < 8; ++i) gc[i] = gn[i];
      cbc[0] = cbn[0]; cbc[1] = cbn[1];
    }
    __syncthreads();   // single barrier: drains next-chunk stage (full-iter slack) + releases buf
  }

  // finalize: merge across the 16-lane group
#pragma unroll
  for (int mk = 1; mk < 16; mk <<= 1) {
#pragma unroll
    for (int g = 0; g < 4; ++g) {
      const float om = __shfl_xor(m1[g], mk);
      const float os = __shfl_xor(s1[g], mk);
      const float ot = __shfl_xor(t1[g], mk);
      pmerge(m1[g], s1[g], t1[g], om, os, ot);
      const float ov1 = __shfl_xor(v1[g], mk);
      const float oi1 = __shfl_xor(i1[g], mk);
      const float ov2 = __shfl_xor(v2[g], mk);
      const float oi2 = __shfl_xor(i2[g], mk);
      const float ov3 = __shfl_xor(v3[g], mk);
      top3_merge(v1[g], i1[g], v2[g], i2[g], v3[g], ov1, oi1, ov2, oi2, ov3);
      s2[g] += __shfl_xor(s2[g], mk);   // mr uniform per group -> plain add
    }
  }
  float klsum = 0.f, cmsum = 0.f;
#pragma unroll
  for (int g = 0; g < 4; ++g) {
    const float commit_row = t1[g] / s1[g];
    const float lse = m1[g] + logf(s1[g]);
    klsum += -commit_row - lse + LOG_SLOTS;
    cmsum += commit_row;
    if (l15 == 0) {
      const int row = rw + lq * 4 + g;
      out[IDX_OFF + row] = i1[g];
      float4 tv; tv.x = v1[g]; tv.y = v2[g]; tv.z = v3[g]; tv.w = i2[g];
      *(float4*)&topw[(size_t)row * 4] = tv;
      normbuf[row] = make_float2(mr[g], 1.f / s2[g]);
    }
  }
  float kw = (l15 == 0) ? klsum : 0.f;
  float cw = (l15 == 0) ? cmsum : 0.f;
#pragma unroll
  for (int mk = 1; mk < 64; mk <<= 1) { kw += __shfl_xor(kw, mk); cw += __shfl_xor(cw, mk); }
  if (lane == 0) {
    atomicAdd(&out[KL_OFF], kw * 0.03125f);
    atomicAdd(&out[CM_OFF], cw * 0.03125f);
  }
}

// k4: PV streaming GEMM, z_q^T = V^T @ u (per-chunk rescale by exp(mr_cf - mr_fin)), no LDS/barriers
__global__ __launch_bounds__(256) __attribute__((amdgpu_waves_per_eu(3, 3)))
void k4_pv(const _Float16* __restrict__ ubig, const float* __restrict__ mrbuf,
           const float2* __restrict__ normbuf, const _Float16* __restrict__ pvs,
           float* __restrict__ out) {
  const int t = threadIdx.x, wv = t >> 6, lane = t & 63, l15 = lane & 15, lq = lane >> 4;
  const int rt = blockIdx.x * 4 + wv;
  const int r0 = rt * 16;
  const int b = r0 >> 11, w0 = r0 & 2047;
  const float2 nv = normbuf[r0 + l15];
  const float mrfin = nv.x, inv = nv.y;
  v4f pacc[16];
#pragma unroll
  for (int dt = 0; dt < 16; ++dt) pacc[dt] = v4f{0.f, 0.f, 0.f, 0.f};

  float mrc = mrbuf[(size_t)rt * 32 * 16 + l15];
  half8_t pa0 = *(const half8_t*)&ubig[(size_t)rt * 32 * 512 + l15 * 32 + lq * 8];
#pragma unroll 1
  for (int cf = 0; cf < 32; ++cf) {
    float mrn = 0.f; half8_t pan = pa0;
    if (cf < 31) {
      mrn = mrbuf[((size_t)rt * 32 + cf + 1) * 16 + l15];
      pan = *(const half8_t*)&ubig[((size_t)rt * 32 + cf + 1) * 512 + l15 * 32 + lq * 8];
    }
    const float f = __expf(mrc - mrfin);
    half8_t pa;
#pragma unroll
    for (int j = 0; j < 8; ++j) pa[j] = (_Float16)((float)pa0[j] * f);
#pragma unroll
    for (int dt = 0; dt < 16; ++dt) {
      const half8_t pb = *(const half8_t*)&pvs[((size_t)(cf * 16 + dt) * 64 + lane) * 8];
      pacc[dt] = __builtin_amdgcn_mfma_f32_16x16x32_f16(pb, pa, pacc[dt], 0, 0, 0);
    }
    mrc = mrn; pa0 = pan;
  }
#pragma unroll
  for (int dt = 0; dt < 16; ++dt)
#pragma unroll
    for (int g = 0; g < 4; ++g)
      out[((size_t)b * DIMD + dt * 16 + lq * 4 + g) * WW + w0 + l15] = pacc[dt][g] * inv;
}

// fp64 argmax repair for near-tie rows
__global__ void k5_repair(const float* __restrict__ z_e, const float* __restrict__ cb,
                          const float* __restrict__ gum, const float* __restrict__ topw,
                          float* __restrict__ out) {
  const int wv = threadIdx.x >> 6, lane = threadIdx.x & 63;
#pragma unroll 1
  for (int rr = 0; rr < 64; ++rr) {
    const int r = blockIdx.x * 256 + wv * 64 + rr;
    const float4 tw = *(const float4*)&topw[(size_t)r * 4];
    if (tw.x - tw.y >= 0.02f) continue;
    const int b = r >> 11, w = r & 2047;
    double zd[4]; double zq = 0.0;
#pragma unroll
    for (int i = 0; i < 4; ++i) {
      const float zz = z_e[((size_t)b * DIMD + lane + i * 64) * WW + w];
      zd[i] = (double)zz; zq += zd[i] * zd[i];
    }
#pragma unroll
    for (int mk = 1; mk < 64; mk <<= 1) zq += __shfl_xor(zq, mk);
    const int c1 = (int)out[IDX_OFF + r];
    const int c2 = (int)tw.w;
    const bool full = (tw.x - tw.z < 0.02f);
    double bestv = -1e300; int besti = 0;
    const int nc = full ? SLOTS : 2;
    for (int ci = 0; ci < nc; ++ci) {
      const int s = full ? ci : (ci == 0 ? c1 : c2);
      double dot = 0.0, csq = 0.0;
#pragma unroll
      for (int i = 0; i < 4; ++i) {
        const double cv = (double)cb[(size_t)s * DIMD + lane + i * 64];
        dot += zd[i] * cv; csq += cv * cv;
      }
#pragma unroll
      for (int mk = 1; mk < 64; mk <<= 1) { dot += __shfl_xor(dot, mk); csq += __shfl_xor(csq, mk); }
      const double y = 2.0 * ((double)gum[(size_t)r * SLOTS + s] - (csq + zq - 2.0 * dot));
      if (y > bestv || (y == bestv && s < besti)) { bestv = y; besti = s; }
    }
    if (lane == 0) out[IDX_OFF + r] = (float)besti;
  }
}

extern "C" void kernel_launch(void* const* d_in, const int* in_sizes, int n_in,
                              void* d_out, int out_size, void* d_ws, size_t ws_size,
                              hipStream_t stream) {
  const float* z_e = (const float*)d_in[0];
  const float* cb  = (const float*)d_in[1];
  const float* gum = (const float*)d_in[2];
  float* out = (float*)d_out;
  char* ws = (char*)d_ws;
  if (ws_size < WS_NEED) {
    hipMemsetAsync(d_out, 0, (size_t)out_size * sizeof(float), stream);
    return;
  }
  _Float16* chs = (_Float16*)(ws + WS_CH);
  _Float16* cls = (_Float16*)(ws + WS_CL);
  _Float16* pvs = (_Float16*)(ws + WS_PV);
  float* cbsq = (float*)(ws + WS_CBSQ);
  float* topw = (float*)(ws + WS_TOP);
  float* mrbuf = (float*)(ws + WS_MR);
  float2* normbuf = (float2*)(ws + WS_NORM);
  _Float16* ubig = (_Float16*)(ws + WS_U);
  k0_zero<<<1, 1, 0, stream>>>(out);
  k2_pack<<<128, 256, 0, stream>>>(cb, chs, cls, pvs, cbsq);
  k3_main<<<1024, 256, 0, stream>>>(z_e, gum, chs, cls, cbsq, ubig, mrbuf, normbuf, topw, out);
  k4_pv<<<1024, 256, 0, stream>>>(ubig, mrbuf, normbuf, pvs, out);
  k5_repair<<<256, 256, 0, stream>>>(z_e, cb, gum, topw, out);
}

// Round 8
// 459.080 us; speedup vs baseline: 1.8809x; 1.0132x over previous
//
#include <hip/hip_runtime.h>

#define BSZ 32
#define DIMD 256
#define WW 2048
#define SLOTS 1024
#define NROWS (BSZ*WW)
#define LOG_SLOTS 6.931471805599453f
#define THR 4.0f

#define ZQ_N (BSZ*DIMD*WW)
#define IDX_OFF ZQ_N
#define KL_OFF (ZQ_N + NROWS)
#define CM_OFF (KL_OFF + 1)

// workspace byte offsets
#define WS_CH   0u
#define WS_CL   524288u
#define WS_PV   1048576u
#define WS_CBSQ 1572864u
#define WS_TOP  1576960u
#define WS_MR   2625536u
#define WS_NORM 11014144u
#define WS_U    11538432u
#define WS_NEED (11538432ull + 134217728ull)

typedef _Float16 half2_t __attribute__((ext_vector_type(2)));
typedef _Float16 half8_t __attribute__((ext_vector_type(8)));
typedef float v4f __attribute__((ext_vector_type(4)));

__device__ __forceinline__ void pmerge(float& m, float& s, float& t, float om, float os, float ot) {
  float M = fmaxf(m, om);
  float ea = __expf(m - M), eb = __expf(om - M);
  s = s * ea + os * eb;
  t = t * ea + ot * eb;
  m = M;
}

__device__ __forceinline__ void top3_merge(float& v1, float& i1, float& v2, float& i2, float& v3,
                                           float ov1, float oi1, float ov2, float oi2, float ov3) {
  bool sw = (ov1 > v1) || (ov1 == v1 && oi1 < i1);
  float a1v = sw ? ov1 : v1, a1i = sw ? oi1 : i1;
  float a2v = sw ? ov2 : v2, a2i = sw ? oi2 : i2;
  float a3v = sw ? ov3 : v3;
  float b1v = sw ? v1 : ov1, b1i = sw ? i1 : oi1;
  float b2v = sw ? v2 : ov2;
  bool a2w = (a2v > b1v) || (a2v == b1v && a2i < b1i);
  v1 = a1v; i1 = a1i;
  v2 = a2w ? a2v : b1v;
  i2 = a2w ? a2i : b1i;
  v3 = a2w ? fmaxf(a3v, b1v) : fmaxf(a2v, b2v);
}

__global__ void k0_zero(float* out) { out[KL_OFF] = 0.f; out[CM_OFF] = 0.f; }

// pack codebook: chs/cls = fp16 hi/lo B-fragment stream for QK^T (chunk-contiguous 16KB tiles);
// pvs = fp16 A-fragment stream for PV; cbsq in fp64->fp32
__global__ void k2_pack(const float* __restrict__ cb, _Float16* __restrict__ chs,
                        _Float16* __restrict__ cls, _Float16* __restrict__ pvs,
                        float* __restrict__ cbsq) {
  const int tid = blockIdx.x * 256 + threadIdx.x;
  if (tid < 32768) {
    const int lane = tid & 63;
    {
      const int ks = (tid >> 6) & 7, sblk = tid >> 9;
      const int col = sblk * 16 + (lane & 15);
      const int k0 = ks * 32 + (lane >> 4) * 8;
      half8_t vh, vl;
#pragma unroll
      for (int j = 0; j < 8; ++j) {
        const float v = cb[(size_t)col * DIMD + k0 + j];
        const _Float16 h = (_Float16)v;
        vh[j] = h;
        vl[j] = (_Float16)(v - (float)h);
      }
      *(half8_t*)&chs[(size_t)tid * 8] = vh;
      *(half8_t*)&cls[(size_t)tid * 8] = vl;
    }
    {
      const int idx = tid >> 6;
      const int cf = idx >> 4, dt = idx & 15;
      const int d = dt * 16 + (lane & 15);
      const int s0 = cf * 32 + (lane >> 4) * 8;
      half8_t vp;
#pragma unroll
      for (int j = 0; j < 8; ++j)
        vp[j] = (_Float16)cb[(size_t)(s0 + j) * DIMD + d];
      *(half8_t*)&pvs[(size_t)tid * 8] = vp;
    }
  }
  if (tid < SLOTS) {
    double a = 0.0;
    for (int i = 0; i < DIMD; ++i) { const double v = (double)cb[(size_t)tid * DIMD + i]; a += v * v; }
    cbsq[tid] = (float)a;
  }
}

// async stage one 16KB chunk (hi+lo) of codebook fragments into LDS (linear, global_load_lds)
__device__ __forceinline__ void stage_chunk(const _Float16* __restrict__ chs,
                                            const _Float16* __restrict__ cls,
                                            _Float16* bsh, _Float16* bsl,
                                            int cf, int wv, int lane) {
  const size_t gbase = (size_t)cf * 8192 + wv * 2048 + lane * 8;
#pragma unroll
  for (int i = 0; i < 4; ++i) {
    __builtin_amdgcn_global_load_lds(
        (const __attribute__((address_space(1))) void*)(chs + gbase + i * 512),
        (__attribute__((address_space(3))) void*)(bsh + wv * 2048 + i * 512), 16, 0, 0);
    __builtin_amdgcn_global_load_lds(
        (const __attribute__((address_space(1))) void*)(cls + gbase + i * 512),
        (__attribute__((address_space(3))) void*)(bsl + wv * 2048 + i * 512), 16, 0, 0);
  }
}

// k3: QK^T (fp16-split MFMA, B staged in LDS) + online probs stats + top3 + u write (fp16).
// amdgpu_waves_per_eu(2) MIN-ONLY: cap 256 regs (allocator relaxed, no squeeze-spill);
// residency set by usage: VGPR~104 -> 4 waves/EU, LDS 38.9KB -> 4 blocks/CU = 16 waves/CU.
__global__ __launch_bounds__(256) __attribute__((amdgpu_waves_per_eu(2)))
void k3_main(const float* __restrict__ z_e, const float* __restrict__ gum,
             const _Float16* __restrict__ chs, const _Float16* __restrict__ cls,
             const float* __restrict__ cbsq, _Float16* __restrict__ ubig,
             float* __restrict__ mrbuf, float2* __restrict__ normbuf,
             float* __restrict__ topw, float* __restrict__ out) {
  __shared__ _Float16 bsh[8192];
  __shared__ _Float16 bsl[8192];
  __shared__ _Float16 ubuf[4][16][44];   // 88B row stride: transpose read conflict-free (R5-R7: 0 conflicts)

  const int t = threadIdx.x, wv = t >> 6, lane = t & 63, l15 = lane & 15, lq = lane >> 4;
  const int r0 = blockIdx.x * 64;
  const int rw = r0 + wv * 16;
  const int rt = blockIdx.x * 4 + wv;
  const int b = r0 >> 11;
  const int w0 = rw & 2047;

  stage_chunk(chs, cls, bsh, bsl, 0, wv, lane);

  // z fragments to registers (fp16 hi/lo split)
  const float* zbase = z_e + (size_t)b * DIMD * WW + w0 + l15;
  half8_t ah[8], al[8];
  float zacc = 0.f;
#pragma unroll
  for (int ks = 0; ks < 8; ++ks) {
#pragma unroll
    for (int j = 0; j < 8; ++j) {
      const float v = zbase[(size_t)(ks * 32 + lq * 8 + j) * WW];
      zacc += v * v;
      const _Float16 h = (_Float16)v;
      ah[ks][j] = h;
      al[ks][j] = (_Float16)(v - (float)h);
    }
  }
  zacc += __shfl_xor(zacc, 16);
  zacc += __shfl_xor(zacc, 32);
  float zs[4];
#pragma unroll
  for (int g = 0; g < 4; ++g) zs[g] = __shfl(zacc, lq * 4 + g);

  float m1[4], s1[4], t1[4], v1[4], v2[4], v3[4], i1[4], i2[4], s2[4], mr[4];
#pragma unroll
  for (int g = 0; g < 4; ++g) {
    m1[g] = -1e30f; s1[g] = 0.f; t1[g] = 0.f;
    v1[g] = -1e30f; v2[g] = -1e30f; v3[g] = -1e30f; i1[g] = 0.f; i2[g] = 0.f;
    s2[g] = 0.f; mr[g] = -1e30f;
  }

  const float* gbase = gum + (size_t)rw * SLOTS;
  float gc[8], cbc[2];
#pragma unroll
  for (int c = 0; c < 2; ++c) {
    cbc[c] = cbsq[c * 16 + l15];
#pragma unroll
    for (int g = 0; g < 4; ++g)
      gc[c * 4 + g] = gbase[(size_t)(lq * 4 + g) * SLOTS + c * 16 + l15];
  }

  __syncthreads();   // stage(0) complete

#pragma unroll 1
  for (int cf = 0; cf < 32; ++cf) {
    // S1: gum/cbsq prefetch for next chunk, then MFMAs on staged B
    float gn[8], cbn[2];
    if (cf < 31) {
#pragma unroll
      for (int c = 0; c < 2; ++c) {
        cbn[c] = cbsq[(cf + 1) * 32 + c * 16 + l15];
#pragma unroll
        for (int g = 0; g < 4; ++g)
          gn[c * 4 + g] = gbase[(size_t)(lq * 4 + g) * SLOTS + (cf + 1) * 32 + c * 16 + l15];
      }
    }
    v4f qh[2], ql[2];
    qh[0] = v4f{0.f, 0.f, 0.f, 0.f}; qh[1] = v4f{0.f, 0.f, 0.f, 0.f};
    ql[0] = v4f{0.f, 0.f, 0.f, 0.f}; ql[1] = v4f{0.f, 0.f, 0.f, 0.f};
#pragma unroll
    for (int ks = 0; ks < 8; ++ks) {
      const int o0 = ((0 * 8 + ks) * 64 + lane) * 8;
      const int o1 = ((1 * 8 + ks) * 64 + lane) * 8;
      const half8_t bh0 = *(const half8_t*)&bsh[o0];
      const half8_t bl0 = *(const half8_t*)&bsl[o0];
      const half8_t bh1 = *(const half8_t*)&bsh[o1];
      const half8_t bl1 = *(const half8_t*)&bsl[o1];
      qh[0] = __builtin_amdgcn_mfma_f32_16x16x32_f16(ah[ks], bh0, qh[0], 0, 0, 0);
      ql[0] = __builtin_amdgcn_mfma_f32_16x16x32_f16(al[ks], bh0, ql[0], 0, 0, 0);
      ql[0] = __builtin_amdgcn_mfma_f32_16x16x32_f16(ah[ks], bl0, ql[0], 0, 0, 0);
      qh[1] = __builtin_amdgcn_mfma_f32_16x16x32_f16(ah[ks], bh1, qh[1], 0, 0, 0);
      ql[1] = __builtin_amdgcn_mfma_f32_16x16x32_f16(al[ks], bh1, ql[1], 0, 0, 0);
      ql[1] = __builtin_amdgcn_mfma_f32_16x16x32_f16(ah[ks], bl1, ql[1], 0, 0, 0);
    }
    __syncthreads();   // all waves done reading LDS B-chunk
    if (cf < 31) stage_chunk(chs, cls, bsh, bsl, cf + 1, wv, lane);

    // S2: epilogue (covers staging latency)
    float yv[8];
    float cmax[4] = {-1e30f, -1e30f, -1e30f, -1e30f};
#pragma unroll
    for (int c = 0; c < 2; ++c) {
      const int col = cf * 32 + c * 16 + l15;
      const float cq = cbc[c];
      const float fc = (float)col;
#pragma unroll
      for (int g = 0; g < 4; ++g) {
        const float dd = cq + zs[g] - 2.f * (qh[c][g] + ql[c][g]);
        const float lv = -dd;
        if (__builtin_expect(lv > m1[g] + 8.f, 0)) {
          const float f = __expf(m1[g] - lv);
          s1[g] *= f; t1[g] *= f; m1[g] = lv;
        }
        const float e = __expf(lv - m1[g]);
        s1[g] += e;
        t1[g] = __fmaf_rn(e, dd, t1[g]);
        const float y = 2.f * (gc[c * 4 + g] - dd);
        yv[c * 4 + g] = y;
        const bool b1 = (y > v1[g]);
        const bool b2 = (y > v2[g]);
        const bool b3 = (y > v3[g]);
        v3[g] = b2 ? v2[g] : (b3 ? y : v3[g]);
        v2[g] = b1 ? v1[g] : (b2 ? y : v2[g]);
        i2[g] = b1 ? i1[g] : (b2 ? fc : i2[g]);
        v1[g] = b1 ? y : v1[g];
        i1[g] = b1 ? fc : i1[g];
        cmax[g] = fmaxf(cmax[g], y);
      }
    }
#pragma unroll
    for (int mk = 1; mk < 16; mk <<= 1)
#pragma unroll
      for (int g = 0; g < 4; ++g) cmax[g] = fmaxf(cmax[g], __shfl_xor(cmax[g], mk));
    // running-max update (uniform per 16-lane group)
#pragma unroll
    for (int g = 0; g < 4; ++g) {
      if (cmax[g] > mr[g] + THR) {
        s2[g] *= __expf(mr[g] - cmax[g]);
        mr[g] = cmax[g];
      }
    }
    // u = exp(y - mr), transpose via wave-local LDS
#pragma unroll
    for (int c = 0; c < 2; ++c)
#pragma unroll
      for (int g = 0; g < 4; ++g) {
        const float u = __expf(yv[c * 4 + g] - mr[g]);
        s2[g] += u;
        ubuf[wv][lq * 4 + g][c * 16 + l15] = (_Float16)u;
      }
    if (l15 == 0) {
#pragma unroll
      for (int g = 0; g < 4; ++g)
        mrbuf[((size_t)rt * 32 + cf) * 16 + lq * 4 + g] = mr[g];
    }
    const half8_t pa = *(const half8_t*)&ubuf[wv][l15][lq * 8];
    *(half8_t*)&ubig[((size_t)rt * 32 + cf) * 512 + l15 * 32 + lq * 8] = pa;
    if (cf < 31) {
#pragma unroll
      for (int i = 0; i < 8; ++i) gc[i] = gn[i];
      cbc[0] = cbn[0]; cbc[1] = cbn[1];
    }
    __syncthreads();   // stage complete before next S1 reads
  }

  // finalize: merge across the 16-lane group
#pragma unroll
  for (int mk = 1; mk < 16; mk <<= 1) {
#pragma unroll
    for (int g = 0; g < 4; ++g) {
      const float om = __shfl_xor(m1[g], mk);
      const float os = __shfl_xor(s1[g], mk);
      const float ot = __shfl_xor(t1[g], mk);
      pmerge(m1[g], s1[g], t1[g], om, os, ot);
      const float ov1 = __shfl_xor(v1[g], mk);
      const float oi1 = __shfl_xor(i1[g], mk);
      const float ov2 = __shfl_xor(v2[g], mk);
      const float oi2 = __shfl_xor(i2[g], mk);
      const float ov3 = __shfl_xor(v3[g], mk);
      top3_merge(v1[g], i1[g], v2[g], i2[g], v3[g], ov1, oi1, ov2, oi2, ov3);
      s2[g] += __shfl_xor(s2[g], mk);   // mr uniform per group -> plain add
    }
  }
  float klsum = 0.f, cmsum = 0.f;
#pragma unroll
  for (int g = 0; g < 4; ++g) {
    const float commit_row = t1[g] / s1[g];
    const float lse = m1[g] + logf(s1[g]);
    klsum += -commit_row - lse + LOG_SLOTS;
    cmsum += commit_row;
    if (l15 == 0) {
      const int row = rw + lq * 4 + g;
      out[IDX_OFF + row] = i1[g];
      float4 tv; tv.x = v1[g]; tv.y = v2[g]; tv.z = v3[g]; tv.w = i2[g];
      *(float4*)&topw[(size_t)row * 4] = tv;
      normbuf[row] = make_float2(mr[g], 1.f / s2[g]);
    }
  }
  float kw = (l15 == 0) ? klsum : 0.f;
  float cw = (l15 == 0) ? cmsum : 0.f;
#pragma unroll
  for (int mk = 1; mk < 64; mk <<= 1) { kw += __shfl_xor(kw, mk); cw += __shfl_xor(cw, mk); }
  if (lane == 0) {
    atomicAdd(&out[KL_OFF], kw * 0.03125f);
    atomicAdd(&out[CM_OFF], cw * 0.03125f);
  }
}

// k4: PV streaming GEMM, z_q^T = V^T @ u (per-chunk rescale by exp(mr_cf - mr_fin)), no LDS/barriers
__global__ __launch_bounds__(256) __attribute__((amdgpu_waves_per_eu(2)))
void k4_pv(const _Float16* __restrict__ ubig, const float* __restrict__ mrbuf,
           const float2* __restrict__ normbuf, const _Float16* __restrict__ pvs,
           float* __restrict__ out) {
  const int t = threadIdx.x, wv = t >> 6, lane = t & 63, l15 = lane & 15, lq = lane >> 4;
  const int rt = blockIdx.x * 4 + wv;
  const int r0 = rt * 16;
  const int b = r0 >> 11, w0 = r0 & 2047;
  const float2 nv = normbuf[r0 + l15];
  const float mrfin = nv.x, inv = nv.y;
  v4f pacc[16];
#pragma unroll
  for (int dt = 0; dt < 16; ++dt) pacc[dt] = v4f{0.f, 0.f, 0.f, 0.f};

  float mrc = mrbuf[(size_t)rt * 32 * 16 + l15];
  half8_t pa0 = *(const half8_t*)&ubig[(size_t)rt * 32 * 512 + l15 * 32 + lq * 8];
#pragma unroll 1
  for (int cf = 0; cf < 32; ++cf) {
    float mrn = 0.f; half8_t pan = pa0;
    if (cf < 31) {
      mrn = mrbuf[((size_t)rt * 32 + cf + 1) * 16 + l15];
      pan = *(const half8_t*)&ubig[((size_t)rt * 32 + cf + 1) * 512 + l15 * 32 + lq * 8];
    }
    const float f = __expf(mrc - mrfin);
    half8_t pa;
#pragma unroll
    for (int j = 0; j < 8; ++j) pa[j] = (_Float16)((float)pa0[j] * f);
#pragma unroll
    for (int dt = 0; dt < 16; ++dt) {
      const half8_t pb = *(const half8_t*)&pvs[((size_t)(cf * 16 + dt) * 64 + lane) * 8];
      pacc[dt] = __builtin_amdgcn_mfma_f32_16x16x32_f16(pb, pa, pacc[dt], 0, 0, 0);
    }
    mrc = mrn; pa0 = pan;
  }
#pragma unroll
  for (int dt = 0; dt < 16; ++dt)
#pragma unroll
    for (int g = 0; g < 4; ++g)
      out[((size_t)b * DIMD + dt * 16 + lq * 4 + g) * WW + w0 + l15] = pacc[dt][g] * inv;
}

// fp64 argmax repair for near-tie rows
__global__ void k5_repair(const float* __restrict__ z_e, const float* __restrict__ cb,
                          const float* __restrict__ gum, const float* __restrict__ topw,
                          float* __restrict__ out) {
  const int wv = threadIdx.x >> 6, lane = threadIdx.x & 63;
#pragma unroll 1
  for (int rr = 0; rr < 64; ++rr) {
    const int r = blockIdx.x * 256 + wv * 64 + rr;
    const float4 tw = *(const float4*)&topw[(size_t)r * 4];
    if (tw.x - tw.y >= 0.02f) continue;
    const int b = r >> 11, w = r & 2047;
    double zd[4]; double zq = 0.0;
#pragma unroll
    for (int i = 0; i < 4; ++i) {
      const float zz = z_e[((size_t)b * DIMD + lane + i * 64) * WW + w];
      zd[i] = (double)zz; zq += zd[i] * zd[i];
    }
#pragma unroll
    for (int mk = 1; mk < 64; mk <<= 1) zq += __shfl_xor(zq, mk);
    const int c1 = (int)out[IDX_OFF + r];
    const int c2 = (int)tw.w;
    const bool full = (tw.x - tw.z < 0.02f);
    double bestv = -1e300; int besti = 0;
    const int nc = full ? SLOTS : 2;
    for (int ci = 0; ci < nc; ++ci) {
      const int s = full ? ci : (ci == 0 ? c1 : c2);
      double dot = 0.0, csq = 0.0;
#pragma unroll
      for (int i = 0; i < 4; ++i) {
        const double cv = (double)cb[(size_t)s * DIMD + lane + i * 64];
        dot += zd[i] * cv; csq += cv * cv;
      }
#pragma unroll
      for (int mk = 1; mk < 64; mk <<= 1) { dot += __shfl_xor(dot, mk); csq += __shfl_xor(csq, mk); }
      const double y = 2.0 * ((double)gum[(size_t)r * SLOTS + s] - (csq + zq - 2.0 * dot));
      if (y > bestv || (y == bestv && s < besti)) { bestv = y; besti = s; }
    }
    if (lane == 0) out[IDX_OFF + r] = (float)besti;
  }
}

extern "C" void kernel_launch(void* const* d_in, const int* in_sizes, int n_in,
                              void* d_out, int out_size, void* d_ws, size_t ws_size,
                              hipStream_t stream) {
  const float* z_e = (const float*)d_in[0];
  const float* cb  = (const float*)d_in[1];
  const float* gum = (const float*)d_in[2];
  float* out = (float*)d_out;
  char* ws = (char*)d_ws;
  if (ws_size < WS_NEED) {
    hipMemsetAsync(d_out, 0, (size_t)out_size * sizeof(float), stream);
    return;
  }
  _Float16* chs = (_Float16*)(ws + WS_CH);
  _Float16* cls = (_Float16*)(ws + WS_CL);
  _Float16* pvs = (_Float16*)(ws + WS_PV);
  float* cbsq = (float*)(ws + WS_CBSQ);
  float* topw = (float*)(ws + WS_TOP);
  float* mrbuf = (float*)(ws + WS_MR);
  float2* normbuf = (float2*)(ws + WS_NORM);
  _Float16* ubig = (_Float16*)(ws + WS_U);
  k0_zero<<<1, 1, 0, stream>>>(out);
  k2_pack<<<128, 256, 0, stream>>>(cb, chs, cls, pvs, cbsq);
  k3_main<<<1024, 256, 0, stream>>>(z_e, gum, chs, cls, cbsq, ubig, mrbuf, normbuf, topw, out);
  k4_pv<<<1024, 256, 0, stream>>>(ubig, mrbuf, normbuf, pvs, out);
  k5_repair<<<256, 256, 0, stream>>>(z_e, cb, gum, topw, out);
}